// Round 6
// baseline (202803.528 us; speedup 1.0000x reference)
//
#include <hip/hip_runtime.h>
#include <stdint.h>

#define BATCH 4096
#define SEGS  512

typedef __attribute__((ext_vector_type(8))) short bf16x8;
typedef __attribute__((ext_vector_type(4))) float f32x4;

#define GLD_LDS16(g, l) \
  __builtin_amdgcn_global_load_lds((const __attribute__((address_space(1))) void*)(g), \
                                   (__attribute__((address_space(3))) void*)(l), 16, 0, 0)

__device__ __forceinline__ unsigned short f2bf(float f){
  unsigned u = __float_as_uint(f);
  u += 0x7FFF + ((u >> 16) & 1);   // RNE
  return (unsigned short)(u >> 16);
}
__device__ __forceinline__ float bf2f(unsigned short s){
  return __uint_as_float(((unsigned)s) << 16);
}
__device__ __forceinline__ float fsigmoid(float x){ return 1.0f / (1.0f + __expf(-x)); }
__device__ __forceinline__ float ftanh(float x){
  float e = __expf(-2.0f * fabsf(x));
  float t = (1.0f - e) / (1.0f + e);
  return copysignf(t, x);
}

// ---------------- prep kernels ----------------

__global__ void prep_cvt(const float* __restrict__ x, short* __restrict__ y, int n){
  int i = blockIdx.x * 256 + threadIdx.x;
  if (i < n) y[i] = (short)f2bf(x[i]);
}

// Reorder gate rows: new row 4*j+g  <-  old row g*512+j  (gate order i,f,g,o)
__global__ void prep_reorder(
    const float* __restrict__ W_ih1, const float* __restrict__ W_hh1,
    const float* __restrict__ b_ih1, const float* __restrict__ b_hh1,
    const float* __restrict__ W_ih2, const float* __restrict__ W_hh2,
    const float* __restrict__ b_ih2, const float* __restrict__ b_hh2,
    short* __restrict__ Wr1, short* __restrict__ W1c,
    short* __restrict__ Wr2i, short* __restrict__ Wr2h,
    float* __restrict__ w1r, float* __restrict__ b1r, float* __restrict__ b2r)
{
  int idx = blockIdx.x * 256 + threadIdx.x;   // over 2048*512
  if (idx >= 2048 * 512) return;
  int rn = idx >> 9;        // new row
  int k  = idx & 511;
  int j = rn >> 2, g = rn & 3;
  int ro = g * 512 + j;     // old row
  Wr1 [idx] = (short)f2bf(W_hh1[(size_t)ro * 512 + k]);
  W1c [idx] = (short)f2bf(W_ih1[(size_t)ro * 514 + k]);   // W_ih1 rows length 514
  Wr2i[idx] = (short)f2bf(W_ih2[(size_t)ro * 512 + k]);
  Wr2h[idx] = (short)f2bf(W_hh2[(size_t)ro * 512 + k]);
  if (k == 0){
    w1r[rn] = W_ih1[(size_t)ro * 514 + 512];
    b1r[rn] = b_ih1[ro] + b_hh1[ro];
    b2r[rn] = b_ih2[ro] + b_hh2[ro];
  }
}

// Pack head weights: Wh[15][512] bf16: rows 0-4 Wmu, 5-9 Wvar, 10-14 Wmix
__global__ void prep_whead(const float* __restrict__ Wmu, const float* __restrict__ Wvar,
                           const float* __restrict__ Wmix, short* __restrict__ Wh){
  int i = blockIdx.x * 256 + threadIdx.x;
  if (i >= 15 * 512) return;
  int n = i >> 9, k = i & 511;
  float v = (n < 5) ? Wmu[n * 512 + k] : (n < 10) ? Wvar[(n - 5) * 512 + k]
          : Wmix[(n - 10) * 512 + k];
  Wh[i] = (short)f2bf(v);
}

// ---------------- prologue GEMM (idea / base1), 128x128 tile ----------------
// mode 0: out bf16 = tanh(C + bias)   row-major [M,N]
// mode 1: out bf16 = C + bias, C-fragment-swizzled: idx=((row>>2)*2048+col)*4+(row&3)
__global__ __launch_bounds__(256) void gemm_pre(
    const short* A, const short* B,
    int N, int mode, const float* bias,
    unsigned short* outp)
{
  __shared__ __align__(16) short As[8192];
  __shared__ __align__(16) short Bs[8192];
  const int tid = threadIdx.x, lane = tid & 63, wave = tid >> 6;
  const int wm = wave >> 1, wn = wave & 1;
  const int m0 = blockIdx.y * 128, n0 = blockIdx.x * 128;

  int aoff[4], boff[4];
  #pragma unroll
  for (int j = 0; j < 4; j++){
    int c = (wave * 4 + j) * 64 + lane;
    int quad = c & 3, r16 = (c >> 2) & 15, kw = (c >> 6) & 1, g = c >> 7;
    int row = g * 16 + r16, col = kw * 32 + quad * 8;
    aoff[j] = (m0 + row) * 512 + col;
    boff[j] = (n0 + row) * 512 + col;
  }
  const int fro = ((lane & 15) * 4 + (lane >> 4)) * 8;

  f32x4 acc[4][4];
  #pragma unroll
  for (int i = 0; i < 4; i++)
    #pragma unroll
    for (int j = 0; j < 4; j++)
      acc[i][j] = (f32x4){0.f, 0.f, 0.f, 0.f};

  for (int it = 0; it < 8; ++it){
    const int kk = it << 6;
    #pragma unroll
    for (int j = 0; j < 4; ++j){
      GLD_LDS16(A + aoff[j] + kk, (char*)As + (wave * 4 + j) * 1024);
      GLD_LDS16(B + boff[j] + kk, (char*)Bs + (wave * 4 + j) * 1024);
    }
    __syncthreads();
    #pragma unroll
    for (int kw = 0; kw < 2; ++kw){
      bf16x8 af[4], bfr[4];
      #pragma unroll
      for (int f = 0; f < 4; f++){
        af[f]  = *(const bf16x8*)&As[((wm * 4 + f) * 2 + kw) * 512 + fro];
        bfr[f] = *(const bf16x8*)&Bs[((wn * 4 + f) * 2 + kw) * 512 + fro];
      }
      #pragma unroll
      for (int mf = 0; mf < 4; mf++)
        #pragma unroll
        for (int nf = 0; nf < 4; nf++)
          acc[mf][nf] = __builtin_amdgcn_mfma_f32_16x16x32_bf16(af[mf], bfr[nf], acc[mf][nf], 0, 0, 0);
    }
    __syncthreads();
  }

  const int lr = (lane >> 4) * 4;
  const int lc = lane & 15;
  #pragma unroll
  for (int mf = 0; mf < 4; mf++)
    #pragma unroll
    for (int nf = 0; nf < 4; nf++)
      #pragma unroll
      for (int r = 0; r < 4; r++){
        int grow = m0 + wm * 64 + mf * 16 + lr + r;
        int gcol = n0 + wn * 64 + nf * 16 + lc;
        float v = acc[mf][nf][r] + bias[gcol];
        if (mode == 0)
          outp[(size_t)grow * N + gcol] = f2bf(ftanh(v));
        else
          outp[((size_t)(grow >> 2) * 2048 + gcol) * 4 + (grow & 3)] = f2bf(v);
      }
}

// ---------------- persistent RNN helpers (R3-proven constructs only) -------

// Single-buffered K-loop: C[128 x 256] += A[128,k]*B[256,k]
// A tile 128x64 (4 chunks/thread), B tile 256x64 (8 chunks/thread).
__device__ __forceinline__ void run_tile256(
    const short* A1, const short* B1, const short* A2, const short* B2,
    int nk1, int nk2, const int* aoff, const int* boff,
    short* As, short* Bs, int wave, int wm, int wn, int fro,
    f32x4 (&acc)[4][8])
{
  #pragma unroll
  for (int i = 0; i < 4; i++)
    #pragma unroll
    for (int j = 0; j < 8; j++)
      acc[i][j] = (f32x4){0.f, 0.f, 0.f, 0.f};

  const int nk = nk1 + nk2;
  for (int it = 0; it < nk; ++it){
    const short* Ap = (it < nk1) ? A1 : A2;
    const short* Bp = (it < nk1) ? B1 : B2;
    const int kk = ((it < nk1) ? it : it - nk1) << 6;
    #pragma unroll
    for (int j = 0; j < 4; ++j)
      GLD_LDS16(Ap + aoff[j] + kk, (char*)As + (wave * 4 + j) * 1024);
    #pragma unroll
    for (int j = 0; j < 8; ++j)
      GLD_LDS16(Bp + boff[j] + kk, (char*)Bs + (wave * 8 + j) * 1024);
    __syncthreads();
    #pragma unroll
    for (int kw = 0; kw < 2; ++kw){
      bf16x8 af[4], bfr[8];
      #pragma unroll
      for (int f = 0; f < 4; f++)
        af[f]  = *(const bf16x8*)&As[((wm * 4 + f) * 2 + kw) * 512 + fro];
      #pragma unroll
      for (int f = 0; f < 8; f++)
        bfr[f] = *(const bf16x8*)&Bs[((wn * 8 + f) * 2 + kw) * 512 + fro];
      #pragma unroll
      for (int mf = 0; mf < 4; mf++)
        #pragma unroll
        for (int nf = 0; nf < 8; nf++)
          acc[mf][nf] = __builtin_amdgcn_mfma_f32_16x16x32_bf16(af[mf], bfr[nf], acc[mf][nf], 0, 0, 0);
    }
    __syncthreads();
  }
}

// m-group barrier (8 peer blocks), device-scope fenced for cross-XCD visibility
__device__ __forceinline__ void mgroup_bar(int* cnt, int target, int tid){
  __syncthreads();
  if (tid == 0){
    __threadfence();
    __hip_atomic_fetch_add(cnt, 1, __ATOMIC_RELEASE, __HIP_MEMORY_SCOPE_AGENT);
    while (__hip_atomic_load(cnt, __ATOMIC_ACQUIRE, __HIP_MEMORY_SCOPE_AGENT) < target)
      __builtin_amdgcn_s_sleep(1);
    __threadfence();
  }
  __syncthreads();
}

// ---------------- persistent RNN (regular launch, 256 blocks = 1/CU) -------
__global__ __launch_bounds__(256, 1) void persistent_rnn(
    short* h1A, short* h1B, short* h2A, short* h2B,
    const short* Wr1, const short* Wr2i, const short* Wr2h,
    const unsigned short* base1,   // C-fragment-swizzled bf16
    const float* w1r, const float* b2r,
    const short* Whead,
    const float* bmu, const float* bvar,
    const float* bmix, const float* eps,
    float* angG, float* c1G, float* c2G,
    int* barA, int* barB, int* flagH,
    float* out)
{
  __shared__ __align__(16) short As[8192];     // 16 KB (128x64)
  __shared__ __align__(16) short Bs[16384];    // 32 KB (256x64)
  __shared__ float headP[16 * 16];
  __shared__ float angSf[128];

  const int tid = threadIdx.x, lane = tid & 63, wave = tid >> 6;
  const int wm = wave >> 1, wn = wave & 1;     // each wave: 64 rows x 128 cols
  const int bid = blockIdx.x;
  const int m_idx = bid >> 3, n_idx = bid & 7; // n_idx == XCD (bid % 8)
  const int m0 = m_idx * 128, n0 = n_idx * 256;

  int aoff[4], boff[8];
  #pragma unroll
  for (int j = 0; j < 4; j++){
    int c = (wave * 4 + j) * 64 + lane;
    int quad = c & 3, r16 = (c >> 2) & 15, kw = (c >> 6) & 1, g = c >> 7;
    aoff[j] = (m0 + g * 16 + r16) * 512 + kw * 32 + quad * 8;
  }
  #pragma unroll
  for (int j = 0; j < 8; j++){
    int c = (wave * 8 + j) * 64 + lane;
    int quad = c & 3, r16 = (c >> 2) & 15, kw = (c >> 6) & 1, g = c >> 7;
    boff[j] = (n0 + g * 16 + r16) * 512 + kw * 32 + quad * 8;
  }
  const int fro = ((lane & 15) * 4 + (lane >> 4)) * 8;
  const int lr = (lane >> 4) * 4;
  const int lc = lane & 15;
  const int q = lane & 3;

  if (tid < 128) angSf[tid] = 0.f;
  __syncthreads();

  f32x4 acc[4][8];
  short* h1buf[2] = {h1A, h1B};
  short* h2buf[2] = {h2A, h2B};
  int cur = 0;

  #pragma clang loop unroll(disable)
  for (int s = 0; s < SEGS; ++s){
    const short* h1c = h1buf[cur];
    short*       h1n = h1buf[cur ^ 1];
    const short* h2c = h2buf[cur];
    short*       h2n = h2buf[cur ^ 1];

    // ---- phase A: gates1 = base1 + ang*w1r + h1 @ Wr1^T ----
    run_tile256(h1c, Wr1, nullptr, nullptr, 8, 0, aoff, boff,
                As, Bs, wave, wm, wn, fro, acc);

    if (s > 0){
      if (tid == 0){
        while (__hip_atomic_load(&flagH[m_idx], __ATOMIC_ACQUIRE, __HIP_MEMORY_SCOPE_AGENT) < 8 * s)
          __builtin_amdgcn_s_sleep(1);
        __threadfence();
      }
      __syncthreads();
      if (tid < 128)
        angSf[tid] = __hip_atomic_load(&angG[m0 + tid], __ATOMIC_RELAXED, __HIP_MEMORY_SCOPE_AGENT);
      __syncthreads();
    }

    {
      unsigned short* hout = (unsigned short*)h1n;
      #pragma unroll
      for (int mf = 0; mf < 4; mf++)
        #pragma unroll
        for (int nf = 0; nf < 8; nf++){
          const int growb = m0 + wm * 64 + mf * 16 + lr;
          const int gcol  = n0 + wn * 128 + nf * 16 + lc;
          const float wv = w1r[gcol];
          ushort4 b4 = *(const ushort4*)&base1[((size_t)(growb >> 2) * 2048 + gcol) * 4];
          const unsigned short bb4[4] = {b4.x, b4.y, b4.z, b4.w};
          #pragma unroll
          for (int r = 0; r < 4; r++){
            int grow = growb + r;
            float v = acc[mf][nf][r] + bf2f(bb4[r]) + angSf[grow - m0] * wv;
            float x1 = __shfl_xor(v, 1);
            float x2 = __shfl_xor(v, 2);
            float x3 = __shfl_xor(v, 3);
            if (q == 0){
              size_t ci = (size_t)grow * 512 + (gcol >> 2);
              float co = c1G[ci];
              float cn = fsigmoid(x1) * co + fsigmoid(v) * ftanh(x2);
              float hn = fsigmoid(x3) * ftanh(cn);
              c1G[ci] = cn;
              hout[ci] = f2bf(hn);
            }
          }
        }
    }
    mgroup_bar(&barA[m_idx], 8 * (s + 1), tid);

    // ---- phase B: gates2 = b2r + h1' @ Wr2i^T + h2 @ Wr2h^T ----
    run_tile256(h1n, Wr2i, h2c, Wr2h, 8, 8, aoff, boff,
                As, Bs, wave, wm, wn, fro, acc);
    {
      unsigned short* hout = (unsigned short*)h2n;
      #pragma unroll
      for (int mf = 0; mf < 4; mf++)
        #pragma unroll
        for (int nf = 0; nf < 8; nf++){
          const int growb = m0 + wm * 64 + mf * 16 + lr;
          const int gcol  = n0 + wn * 128 + nf * 16 + lc;
          const float bv = b2r[gcol];
          #pragma unroll
          for (int r = 0; r < 4; r++){
            int grow = growb + r;
            float v = acc[mf][nf][r] + bv;
            float x1 = __shfl_xor(v, 1);
            float x2 = __shfl_xor(v, 2);
            float x3 = __shfl_xor(v, 3);
            if (q == 0){
              size_t ci = (size_t)grow * 512 + (gcol >> 2);
              float co = c2G[ci];
              float cn = fsigmoid(x1) * co + fsigmoid(v) * ftanh(x2);
              float hn = fsigmoid(x3) * ftanh(cn);
              c2G[ci] = cn;
              hout[ci] = f2bf(hn);
            }
          }
        }
    }
    mgroup_bar(&barB[m_idx], 8 * (s + 1), tid);

    // ---- distributed head: this block does 16 rows of its m-strip ----
    {
      const int rr = tid & 15, o = tid >> 4;   // o in [0,16)
      const int row = m0 + n_idx * 16 + rr;
      if (o < 15){
        float pv = 0.f;
        const unsigned short* hp = (const unsigned short*)h2n + (size_t)row * 512;
        const unsigned short* wp = (const unsigned short*)Whead + o * 512;
        for (int k = 0; k < 64; k++){
          uint4 hv = *(const uint4*)(hp + k * 8);
          uint4 wv = *(const uint4*)(wp + k * 8);
          const unsigned short* hh = (const unsigned short*)&hv;
          const unsigned short* ww = (const unsigned short*)&wv;
          #pragma unroll
          for (int e = 0; e < 8; e++)
            pv += bf2f(hh[e]) * bf2f(ww[e]);
        }
        headP[rr * 16 + o] = pv;
      }
      __syncthreads();
      if (tid < 16){
        float pp[15];
        #pragma unroll
        for (int k = 0; k < 15; k++) pp[k] = headP[tid * 16 + k];
        float l[5], mx = -1e30f;
        #pragma unroll
        for (int k = 0; k < 5; k++){ l[k] = pp[10 + k] + bmix[k]; mx = fmaxf(mx, l[k]); }
        float se = 0.f, e5[5];
        #pragma unroll
        for (int k = 0; k < 5; k++){ e5[k] = __expf(l[k] - mx); se += e5[k]; }
        float inv = 1.0f / se, mu = 0.f, sg = 0.f;
        #pragma unroll
        for (int k = 0; k < 5; k++){
          float rho = e5[k] * inv;
          mu += rho * (pp[k] + bmu[k]);
          sg += rho * __expf(pp[5 + k] + bvar[k]);   // t = 0
        }
        const int row2 = m0 + n_idx * 16 + tid;
        float a = ftanh(mu + sg * eps[(size_t)s * BATCH + row2]);
        __hip_atomic_store(&angG[row2], a, __ATOMIC_RELAXED, __HIP_MEMORY_SCOPE_AGENT);
        size_t oo = ((size_t)row2 * SEGS + s) * 2;
        out[oo] = a; out[oo + 1] = 0.0f;
      }
      __syncthreads();
      if (tid == 0){
        __threadfence();
        __hip_atomic_fetch_add(&flagH[m_idx], 1, __ATOMIC_RELEASE, __HIP_MEMORY_SCOPE_AGENT);
      }
    }
    cur ^= 1;
  }
}

// ---------------- launch ----------------

extern "C" void kernel_launch(void* const* d_in, const int* in_sizes, int n_in,
                              void* d_out, int out_size, void* d_ws, size_t ws_size,
                              hipStream_t stream)
{
  const float* latent   = (const float*)d_in[0];
  const float* W_unpack = (const float*)d_in[1];
  const float* b_unpack = (const float*)d_in[2];
  const float* W_ih1    = (const float*)d_in[3];
  const float* W_hh1    = (const float*)d_in[4];
  const float* b_ih1    = (const float*)d_in[5];
  const float* b_hh1    = (const float*)d_in[6];
  const float* W_ih2    = (const float*)d_in[7];
  const float* W_hh2    = (const float*)d_in[8];
  const float* b_ih2    = (const float*)d_in[9];
  const float* b_hh2    = (const float*)d_in[10];
  const float* W_mu     = (const float*)d_in[11];
  const float* b_mu     = (const float*)d_in[12];
  const float* W_var    = (const float*)d_in[13];
  const float* b_var    = (const float*)d_in[14];
  const float* W_mix    = (const float*)d_in[15];
  const float* b_mix    = (const float*)d_in[16];
  const float* eps      = (const float*)d_in[17];
  float* out = (float*)d_out;

  char* p = (char*)d_ws;
  auto alloc = [&](size_t b) -> void* {
    void* r = (void*)p;
    p += (b + 255) & ~(size_t)255;
    return r;
  };
  short* latb  = (short*)alloc((size_t)BATCH * 512 * 2);
  short* Wub   = (short*)alloc((size_t)512 * 512 * 2);
  short* idea  = (short*)alloc((size_t)BATCH * 512 * 2);
  unsigned short* base1 = (unsigned short*)alloc((size_t)BATCH * 2048 * 2);
  short* Wr1   = (short*)alloc((size_t)2048 * 512 * 2);
  short* W1c   = (short*)alloc((size_t)2048 * 512 * 2);
  short* Wr2i  = (short*)alloc((size_t)2048 * 512 * 2);
  short* Wr2h  = (short*)alloc((size_t)2048 * 512 * 2);
  short* Whead = (short*)alloc((size_t)15 * 512 * 2);
  float* w1r   = (float*)alloc(2048 * 4);
  float* b1r   = (float*)alloc(2048 * 4);
  float* b2r   = (float*)alloc(2048 * 4);
  short* h1a   = (short*)alloc((size_t)BATCH * 512 * 2);
  short* h1b   = (short*)alloc((size_t)BATCH * 512 * 2);
  short* h2a   = (short*)alloc((size_t)BATCH * 512 * 2);
  short* h2b   = (short*)alloc((size_t)BATCH * 512 * 2);
  float* c1    = (float*)alloc((size_t)BATCH * 512 * 4);
  float* c2    = (float*)alloc((size_t)BATCH * 512 * 4);
  float* ang   = (float*)alloc(BATCH * 4);
  int*   barA  = (int*)alloc(32 * 4);
  int*   barB  = (int*)alloc(32 * 4);
  int*   flagH = (int*)alloc(32 * 4);

  (void)hipMemsetAsync(h1a, 0, (size_t)BATCH * 512 * 2, stream);
  (void)hipMemsetAsync(h2a, 0, (size_t)BATCH * 512 * 2, stream);
  (void)hipMemsetAsync(c1, 0, (size_t)BATCH * 512 * 4, stream);
  (void)hipMemsetAsync(c2, 0, (size_t)BATCH * 512 * 4, stream);
  (void)hipMemsetAsync(barA, 0, 32 * 4, stream);
  (void)hipMemsetAsync(barB, 0, 32 * 4, stream);
  (void)hipMemsetAsync(flagH, 0, 32 * 4, stream);

  prep_cvt<<<(BATCH * 512) / 256, 256, 0, stream>>>(latent, latb, BATCH * 512);
  prep_cvt<<<(512 * 512) / 256, 256, 0, stream>>>(W_unpack, Wub, 512 * 512);
  prep_reorder<<<(2048 * 512) / 256, 256, 0, stream>>>(
      W_ih1, W_hh1, b_ih1, b_hh1, W_ih2, W_hh2, b_ih2, b_hh2,
      Wr1, W1c, Wr2i, Wr2h, w1r, b1r, b2r);
  prep_whead<<<30, 256, 0, stream>>>(W_mu, W_var, W_mix, Whead);

  // idea = tanh(latent @ W_unpack^T + b_unpack)
  gemm_pre<<<dim3(4, 32), 256, 0, stream>>>(latb, Wub, 512, 0, b_unpack,
                                            (unsigned short*)idea);
  // base1 = idea @ W1c^T + (b_ih1+b_hh1), C-fragment-swizzled bf16
  gemm_pre<<<dim3(16, 32), 256, 0, stream>>>(idea, W1c, 2048, 1, b1r, base1);

  persistent_rnn<<<256, 256, 0, stream>>>(
      h1a, h1b, h2a, h2b, Wr1, Wr2i, Wr2h, base1, w1r, b2r,
      Whead, b_mu, b_var, b_mix, eps, ang, c1, c2, barA, barB, flagH, out);
}